// Round 1
// baseline (894.844 us; speedup 1.0000x reference)
//
#include <hip/hip_runtime.h>
#include <hip/hip_bf16.h>

#define NROWS 100000

typedef __attribute__((ext_vector_type(8))) short bf16x8;
typedef __attribute__((ext_vector_type(4))) float f32x4;

__device__ __forceinline__ short f2b(float f) {
  __hip_bfloat16 h = __float2bfloat16(f);
  short s;
  __builtin_memcpy(&s, &h, sizeof(s));
  return s;
}

__device__ __forceinline__ float sigf(float x) { return 1.f / (1.f + __expf(-x)); }
// robust tanh: no inf/inf NaN for large |x|
__device__ __forceinline__ float tanh_f(float x) { return 1.f - 2.f / (__expf(2.f * x) + 1.f); }

// ---------------- weight packing ----------------
// B1: [ct=48][kt=18][lane=64][b=8] bf16, value = W1[k][col], k=kt*32+(lane>>4)*8+b,
//     col: gate=ct/12, m=(ct%12)*16+(lane&15); W1 rows: e(300)|tag(50)|tagp(50)|h(168)|pad(8)
// B2: [ct=60][kt=14][lane=64][b=8] bf16, W2 rows: tag(50)|tagp(50)|h1(168)|k(168)|pad(12)
__global__ void pack_weights(const float* __restrict__ We_l, const float* __restrict__ Wt_l,
                             const float* __restrict__ Wtp_l, const float* __restrict__ Uh_l,
                             const float* __restrict__ Wt_n, const float* __restrict__ Wtp_n,
                             const float* __restrict__ Uh_n, const float* __restrict__ Uk_n,
                             unsigned short* __restrict__ B1, unsigned short* __restrict__ B2) {
  const int NB1 = 48 * 18 * 512;
  const int NB2 = 60 * 14 * 512;
  int idx = blockIdx.x * blockDim.x + threadIdx.x;
  if (idx < NB1) {
    int b = idx & 7, lane = (idx >> 3) & 63, t = idx >> 9;
    int kt = t % 18, ct = t / 18;
    int k = kt * 32 + (lane >> 4) * 8 + b;
    int gate = ct / 12, m = (ct % 12) * 16 + (lane & 15);
    float v = 0.f;
    if (m < 168 && k < 568) {
      int col = gate * 168 + m;
      if (k < 300)      v = We_l[k * 672 + col];
      else if (k < 350) v = Wt_l[(k - 300) * 672 + col];
      else if (k < 400) v = Wtp_l[(k - 350) * 672 + col];
      else              v = Uh_l[(k - 400) * 672 + col];
    }
    B1[idx] = (unsigned short)f2b(v);
  } else if (idx < NB1 + NB2) {
    int j = idx - NB1;
    int b = j & 7, lane = (j >> 3) & 63, t = j >> 9;
    int kt = t % 14, ct = t / 14;
    int k = kt * 32 + (lane >> 4) * 8 + b;
    int gate = ct / 12, m = (ct % 12) * 16 + (lane & 15);
    float v = 0.f;
    if (m < 168 && k < 436) {
      int col = gate * 168 + m;
      if (k < 50)       v = Wt_n[k * 840 + col];
      else if (k < 100) v = Wtp_n[(k - 50) * 840 + col];
      else if (k < 268) v = Uh_n[(k - 100) * 840 + col];
      else if (gate < 4) v = Uk_n[(k - 268) * 672 + gate * 168 + m];
    }
    B2[j] = (unsigned short)f2b(v);
  }
}

// ---------------- A gathers (f32 sources -> bf16 fragment) ----------------
// X1 row = [e(0:300) | tag(300:350) | tagp(350:400) | h_prev(400:568) | 0(568:576)]
__device__ __forceinline__ bf16x8 gatherX1(const float* __restrict__ e, const float* __restrict__ tg,
                                           const float* __restrict__ tp, const float* __restrict__ hp,
                                           int row, int k0) {
  bf16x8 r;
  if (k0 + 8 <= 300) {
    const float* p = e + row * 300 + k0;
    float4 a = *(const float4*)p;
    float4 b = *(const float4*)(p + 4);
    r[0] = f2b(a.x); r[1] = f2b(a.y); r[2] = f2b(a.z); r[3] = f2b(a.w);
    r[4] = f2b(b.x); r[5] = f2b(b.y); r[6] = f2b(b.z); r[7] = f2b(b.w);
  } else if (k0 >= 400) {
    if (k0 >= 568) {
#pragma unroll
      for (int b = 0; b < 8; ++b) r[b] = 0;
    } else {
      const float* p = hp + row * 168 + (k0 - 400);
      float4 a = *(const float4*)p;
      float4 b = *(const float4*)(p + 4);
      r[0] = f2b(a.x); r[1] = f2b(a.y); r[2] = f2b(a.z); r[3] = f2b(a.w);
      r[4] = f2b(b.x); r[5] = f2b(b.y); r[6] = f2b(b.z); r[7] = f2b(b.w);
    }
  } else {
#pragma unroll
    for (int b = 0; b < 8; ++b) {
      int k = k0 + b;
      float v;
      if (k < 300)      v = e[row * 300 + k];
      else if (k < 350) v = tg[row * 50 + (k - 300)];
      else              v = tp[row * 50 + (k - 350)];
      r[b] = f2b(v);
    }
  }
  return r;
}

// X2 row = [tag(0:50) | tagp(50:100) | h1 bf16(100:268) | k(268:436) | 0(436:448)]
__device__ __forceinline__ bf16x8 gatherX2(const float* __restrict__ tg, const float* __restrict__ tp,
                                           const unsigned short* __restrict__ h1,
                                           const float* __restrict__ kk, int row, int k0) {
  bf16x8 r;
  if (k0 >= 104 && k0 <= 260) {
    const unsigned short* p = h1 + row * 168 + (k0 - 100);
    ushort4 a = ((const ushort4*)p)[0];
    ushort4 b = ((const ushort4*)p)[1];
    r[0] = (short)a.x; r[1] = (short)a.y; r[2] = (short)a.z; r[3] = (short)a.w;
    r[4] = (short)b.x; r[5] = (short)b.y; r[6] = (short)b.z; r[7] = (short)b.w;
  } else if (k0 >= 272 && k0 <= 428) {
    const float* p = kk + row * 168 + (k0 - 268);
    float4 a = *(const float4*)p;
    float4 b = *(const float4*)(p + 4);
    r[0] = f2b(a.x); r[1] = f2b(a.y); r[2] = f2b(a.z); r[3] = f2b(a.w);
    r[4] = f2b(b.x); r[5] = f2b(b.y); r[6] = f2b(b.z); r[7] = f2b(b.w);
  } else if (k0 >= 440) {
#pragma unroll
    for (int b = 0; b < 8; ++b) r[b] = 0;
  } else {
#pragma unroll
    for (int b = 0; b < 8; ++b) {
      int k = k0 + b;
      short s;
      if (k < 50)       s = f2b(tg[row * 50 + k]);
      else if (k < 100) s = f2b(tp[row * 50 + (k - 50)]);
      else if (k < 268) s = (short)h1[row * 168 + (k - 100)];
      else if (k < 436) s = f2b(kk[row * 168 + (k - 268)]);
      else              s = 0;
      r[b] = s;
    }
  }
  return r;
}

// ---------------- GEMM1: leaf cell ----------------
// block = 64 rows, 8 waves = 2 row-waves x 4 col-waves; wave = 32 rows x (4 gates x 48 m-cols)
__global__ __launch_bounds__(512) void gemm1_kernel(
    const float* __restrict__ e, const float* __restrict__ tg, const float* __restrict__ tp,
    const float* __restrict__ hp, const float* __restrict__ cprev, const float* __restrict__ b_l,
    const unsigned short* __restrict__ B1, float* __restrict__ c1buf,
    unsigned short* __restrict__ h1buf) {
  const int wave = threadIdx.x >> 6;
  const int ln = threadIdx.x & 63;
  const int rw = wave >> 2, wcol = wave & 3;
  const int rbase = blockIdx.x * 64 + rw * 32;
  const int c = ln & 15, rg = ln >> 4;

  f32x4 acc[2][12];
  const f32x4 z4 = {0.f, 0.f, 0.f, 0.f};
#pragma unroll
  for (int a = 0; a < 2; ++a)
#pragma unroll
    for (int t = 0; t < 12; ++t) acc[a][t] = z4;

  int r0 = rbase + c;      if (r0 >= NROWS) r0 = NROWS - 1;
  int r1 = rbase + 16 + c; if (r1 >= NROWS) r1 = NROWS - 1;

#pragma unroll
  for (int kt = 0; kt < 18; ++kt) {
    const int k0 = kt * 32 + rg * 8;
    bf16x8 a0 = gatherX1(e, tg, tp, hp, r0, k0);
    bf16x8 a1 = gatherX1(e, tg, tp, hp, r1, k0);
#pragma unroll
    for (int t = 0; t < 12; ++t) {
      const int gate = t / 3, mtl = t % 3;
      const int ct = gate * 12 + wcol * 3 + mtl;
      bf16x8 bb = *(const bf16x8*)(B1 + (((ct * 18 + kt) << 6) + ln) * 8);
      acc[0][t] = __builtin_amdgcn_mfma_f32_16x16x32_bf16(a0, bb, acc[0][t], 0, 0, 0);
      acc[1][t] = __builtin_amdgcn_mfma_f32_16x16x32_bf16(a1, bb, acc[1][t], 0, 0, 0);
    }
  }

#pragma unroll
  for (int rt = 0; rt < 2; ++rt) {
#pragma unroll
    for (int mtl = 0; mtl < 3; ++mtl) {
      const int m = wcol * 48 + mtl * 16 + c;
      if (m >= 168) continue;
      const float bi = b_l[m];
      const float bo = b_l[168 + m];
      const float bf_ = b_l[336 + m];
      const float bu = b_l[504 + m];
#pragma unroll
      for (int reg = 0; reg < 4; ++reg) {
        const int row = rbase + rt * 16 + rg * 4 + reg;
        if (row >= NROWS) continue;
        const float iv = acc[rt][0 + mtl][reg] + bi;
        const float ov = acc[rt][3 + mtl][reg] + bo;
        const float fv = acc[rt][6 + mtl][reg] + bf_;
        const float uv = acc[rt][9 + mtl][reg] + bu;
        const float cp = cprev[row * 168 + m];
        const float c1 = sigf(iv) * tanh_f(uv) + sigf(fv) * cp;
        const float h1 = sigf(ov) * tanh_f(c1);
        c1buf[row * 168 + m] = c1;
        h1buf[row * 168 + m] = (unsigned short)f2b(h1);
      }
    }
  }
}

// ---------------- GEMM2: node cell ----------------
__global__ __launch_bounds__(512) void gemm2_kernel(
    const float* __restrict__ tg, const float* __restrict__ tp, const float* __restrict__ kk,
    const float* __restrict__ q, const float* __restrict__ b_n,
    const unsigned short* __restrict__ B2, const float* __restrict__ c1buf,
    const unsigned short* __restrict__ h1buf, float* __restrict__ out) {
  const int wave = threadIdx.x >> 6;
  const int ln = threadIdx.x & 63;
  const int rw = wave >> 2, wcol = wave & 3;
  const int rbase = blockIdx.x * 64 + rw * 32;
  const int c = ln & 15, rg = ln >> 4;

  f32x4 acc[2][15];
  const f32x4 z4 = {0.f, 0.f, 0.f, 0.f};
#pragma unroll
  for (int a = 0; a < 2; ++a)
#pragma unroll
    for (int t = 0; t < 15; ++t) acc[a][t] = z4;

  int r0 = rbase + c;      if (r0 >= NROWS) r0 = NROWS - 1;
  int r1 = rbase + 16 + c; if (r1 >= NROWS) r1 = NROWS - 1;

#pragma unroll
  for (int kt = 0; kt < 14; ++kt) {
    const int k0 = kt * 32 + rg * 8;
    bf16x8 a0 = gatherX2(tg, tp, h1buf, kk, r0, k0);
    bf16x8 a1 = gatherX2(tg, tp, h1buf, kk, r1, k0);
#pragma unroll
    for (int t = 0; t < 15; ++t) {
      const int gate = t / 3, mtl = t % 3;
      const int ct = gate * 12 + wcol * 3 + mtl;
      bf16x8 bb = *(const bf16x8*)(B2 + (((ct * 14 + kt) << 6) + ln) * 8);
      acc[0][t] = __builtin_amdgcn_mfma_f32_16x16x32_bf16(a0, bb, acc[0][t], 0, 0, 0);
      acc[1][t] = __builtin_amdgcn_mfma_f32_16x16x32_bf16(a1, bb, acc[1][t], 0, 0, 0);
    }
  }

#pragma unroll
  for (int rt = 0; rt < 2; ++rt) {
#pragma unroll
    for (int mtl = 0; mtl < 3; ++mtl) {
      const int m = wcol * 48 + mtl * 16 + c;
      if (m >= 168) continue;
      const float bi = b_n[m];
      const float bo = b_n[168 + m];
      const float bfl = b_n[336 + m];
      const float bfd = b_n[504 + m];
      const float bu = b_n[672 + m];
#pragma unroll
      for (int reg = 0; reg < 4; ++reg) {
        const int row = rbase + rt * 16 + rg * 4 + reg;
        if (row >= NROWS) continue;
        const float i2 = acc[rt][0 + mtl][reg] + bi;
        const float o2 = acc[rt][3 + mtl][reg] + bo;
        const float fl2 = acc[rt][6 + mtl][reg] + bfl;
        const float fd2 = acc[rt][9 + mtl][reg] + bfd;
        const float u2 = acc[rt][12 + mtl][reg] + bu;
        const int off = row * 168 + m;
        const float c1 = c1buf[off];
        const float qv = q[off];
        const float c2 = sigf(i2) * tanh_f(u2) + sigf(fd2) * qv + sigf(fl2) * c1;
        const float h2 = sigf(o2) * tanh_f(c2);
        out[row * 336 + m] = h2;
        out[row * 336 + 168 + m] = c2;
      }
    }
  }
}

extern "C" void kernel_launch(void* const* d_in, const int* in_sizes, int n_in,
                              void* d_out, int out_size, void* d_ws, size_t ws_size,
                              hipStream_t stream) {
  const float* e     = (const float*)d_in[0];
  const float* tag   = (const float*)d_in[1];
  const float* tagp  = (const float*)d_in[2];
  const float* hprev = (const float*)d_in[3];
  const float* cprev = (const float*)d_in[4];
  const float* kk    = (const float*)d_in[5];
  const float* q     = (const float*)d_in[6];
  const float* We_l  = (const float*)d_in[7];
  const float* Wt_l  = (const float*)d_in[8];
  const float* Wtp_l = (const float*)d_in[9];
  const float* Uh_l  = (const float*)d_in[10];
  const float* b_l   = (const float*)d_in[11];
  const float* Wt_n  = (const float*)d_in[12];
  const float* Wtp_n = (const float*)d_in[13];
  const float* Uh_n  = (const float*)d_in[14];
  const float* Uk_n  = (const float*)d_in[15];
  const float* b_n   = (const float*)d_in[16];
  float* out = (float*)d_out;

  char* ws = (char*)d_ws;
  unsigned short* B1 = (unsigned short*)ws;                       // 884,736 B
  unsigned short* B2 = (unsigned short*)(ws + (1 << 20));         // 860,160 B
  float* c1buf = (float*)(ws + (2 << 20));                        // 67,200,000 B
  unsigned short* h1buf = (unsigned short*)(ws + (2 << 20) + 67200000); // 33,600,000 B

  const int NB = 48 * 18 * 512 + 60 * 14 * 512;
  pack_weights<<<(NB + 255) / 256, 256, 0, stream>>>(We_l, Wt_l, Wtp_l, Uh_l,
                                                     Wt_n, Wtp_n, Uh_n, Uk_n, B1, B2);

  const int nblk = (NROWS + 63) / 64;  // 1563
  gemm1_kernel<<<nblk, 512, 0, stream>>>(e, tag, tagp, hprev, cprev, b_l, B1, c1buf, h1buf);
  gemm2_kernel<<<nblk, 512, 0, stream>>>(tag, tagp, kk, q, b_n, B2, c1buf, h1buf, out);
}

// Round 2
// 684.975 us; speedup vs baseline: 1.3064x; 1.3064x over previous
//
#include <hip/hip_runtime.h>
#include <hip/hip_bf16.h>

#define NROWS 100000

typedef __attribute__((ext_vector_type(8))) short bf16x8;
typedef __attribute__((ext_vector_type(4))) float f32x4;
typedef float f32x4u __attribute__((ext_vector_type(4), aligned(8)));
typedef unsigned short u16x4u __attribute__((ext_vector_type(4), aligned(8)));

__device__ __forceinline__ short f2b(float f) {
  __hip_bfloat16 h = __float2bfloat16(f);
  short s;
  __builtin_memcpy(&s, &h, sizeof(s));
  return s;
}

__device__ __forceinline__ float sigf(float x) { return 1.f / (1.f + __expf(-x)); }
__device__ __forceinline__ float tanh_f(float x) { return 1.f - 2.f / (__expf(2.f * x) + 1.f); }

__device__ __forceinline__ void gload_lds16(const void* g, void* l) {
  __builtin_amdgcn_global_load_lds((const __attribute__((address_space(1))) unsigned int*)g,
                                   (__attribute__((address_space(3))) unsigned int*)l, 16, 0, 0);
}

__device__ __forceinline__ bf16x8 ld8f(const float* __restrict__ p) {
  f32x4u a = *(const f32x4u*)p;
  f32x4u b = *(const f32x4u*)(p + 4);
  bf16x8 r;
  r[0] = f2b(a[0]); r[1] = f2b(a[1]); r[2] = f2b(a[2]); r[3] = f2b(a[3]);
  r[4] = f2b(b[0]); r[5] = f2b(b[1]); r[6] = f2b(b[2]); r[7] = f2b(b[3]);
  return r;
}

__device__ __forceinline__ bf16x8 ld8h(const unsigned short* __restrict__ p) {
  u16x4u a = *(const u16x4u*)p;
  u16x4u b = *(const u16x4u*)(p + 4);
  bf16x8 r;
  r[0] = (short)a[0]; r[1] = (short)a[1]; r[2] = (short)a[2]; r[3] = (short)a[3];
  r[4] = (short)b[0]; r[5] = (short)b[1]; r[6] = (short)b[2]; r[7] = (short)b[3];
  return r;
}

// ---------------- weight packing ----------------
// B1: [kt=18][ct=48][lane=64][b=8] bf16; k = kt*32+(lane>>4)*8+b; gate=ct/12,
//     m=(ct%12)*16+(lane&15) (m<168 real, else 0). W1 rows: e|tag|tagp|h (568, pad 576).
// B2: [kt=14][ct=64][lane=64][b=8] bf16; ct<60 real (5 gates x 12 mtiles);
//     W2 rows: tag|tagp|h1|k (436, pad 448). Uk only on gates 0-3.
__global__ void pack_weights(const float* __restrict__ We_l, const float* __restrict__ Wt_l,
                             const float* __restrict__ Wtp_l, const float* __restrict__ Uh_l,
                             const float* __restrict__ Wt_n, const float* __restrict__ Wtp_n,
                             const float* __restrict__ Uh_n, const float* __restrict__ Uk_n,
                             unsigned short* __restrict__ B1, unsigned short* __restrict__ B2) {
  const int NB1 = 18 * 48 * 512;
  const int NB2 = 14 * 64 * 512;
  int idx = blockIdx.x * blockDim.x + threadIdx.x;
  if (idx < NB1) {
    int b = idx & 7, lane = (idx >> 3) & 63, t = idx >> 9;
    int ct = t % 48, kt = t / 48;
    int k = kt * 32 + ((lane >> 4) << 3) + b;
    int gate = ct / 12, m = (ct % 12) * 16 + (lane & 15);
    float v = 0.f;
    if (m < 168 && k < 568) {
      int col = gate * 168 + m;
      if (k < 300)      v = We_l[k * 672 + col];
      else if (k < 350) v = Wt_l[(k - 300) * 672 + col];
      else if (k < 400) v = Wtp_l[(k - 350) * 672 + col];
      else              v = Uh_l[(k - 400) * 672 + col];
    }
    B1[idx] = (unsigned short)f2b(v);
  } else if (idx < NB1 + NB2) {
    int j = idx - NB1;
    int b = j & 7, lane = (j >> 3) & 63, t = j >> 9;
    int ct = t % 64, kt = t / 64;
    int k = kt * 32 + ((lane >> 4) << 3) + b;
    int gate = ct / 12, m = (ct % 12) * 16 + (lane & 15);
    float v = 0.f;
    if (ct < 60 && m < 168 && k < 436) {
      int col = gate * 168 + m;
      if (k < 50)        v = Wt_n[k * 840 + col];
      else if (k < 100)  v = Wtp_n[(k - 50) * 840 + col];
      else if (k < 268)  v = Uh_n[(k - 100) * 840 + col];
      else if (gate < 4) v = Uk_n[(k - 268) * 672 + gate * 168 + m];
    }
    B2[j] = (unsigned short)f2b(v);
  }
}

// ---------------- A gathers (k0 is compile-time after full unroll) ----------------
// X1 row = [e(0:300) | tag(300:350) | tagp(350:400) | h_prev(400:568) | 0]
__device__ __forceinline__ bf16x8 gatherX1(const float* __restrict__ e, const float* __restrict__ tg,
                                           const float* __restrict__ tp, const float* __restrict__ hp,
                                           int row, int k0) {
  if (k0 + 8 <= 300)             return ld8f(e + row * 300 + k0);
  if (k0 >= 300 && k0 + 8 <= 350) return ld8f(tg + row * 50 + (k0 - 300));
  if (k0 >= 350 && k0 + 8 <= 400) return ld8f(tp + row * 50 + (k0 - 350));
  if (k0 >= 400 && k0 + 8 <= 568) return ld8f(hp + row * 168 + (k0 - 400));
  if (k0 >= 568) {
    bf16x8 z;
#pragma unroll
    for (int b = 0; b < 8; ++b) z[b] = 0;
    return z;
  }
  bf16x8 r;
#pragma unroll
  for (int b = 0; b < 8; ++b) {
    int k = k0 + b;
    float v;
    if (k < 300)      v = e[row * 300 + k];
    else if (k < 350) v = tg[row * 50 + (k - 300)];
    else if (k < 400) v = tp[row * 50 + (k - 350)];
    else if (k < 568) v = hp[row * 168 + (k - 400)];
    else              v = 0.f;
    r[b] = f2b(v);
  }
  return r;
}

// X2 row = [tag(0:50) | tagp(50:100) | h1 bf16(100:268) | k(268:436) | 0]
__device__ __forceinline__ bf16x8 gatherX2(const float* __restrict__ tg, const float* __restrict__ tp,
                                           const unsigned short* __restrict__ h1,
                                           const float* __restrict__ kk, int row, int k0) {
  if (k0 + 8 <= 50)               return ld8f(tg + row * 50 + k0);
  if (k0 >= 50 && k0 + 8 <= 100)  return ld8f(tp + row * 50 + (k0 - 50));
  if (k0 >= 100 && k0 + 8 <= 268) return ld8h(h1 + row * 168 + (k0 - 100));
  if (k0 >= 268 && k0 + 8 <= 436) return ld8f(kk + row * 168 + (k0 - 268));
  if (k0 >= 436) {
    bf16x8 z;
#pragma unroll
    for (int b = 0; b < 8; ++b) z[b] = 0;
    return z;
  }
  bf16x8 r;
#pragma unroll
  for (int b = 0; b < 8; ++b) {
    int k = k0 + b;
    short s;
    if (k < 50)       s = f2b(tg[row * 50 + k]);
    else if (k < 100) s = f2b(tp[row * 50 + (k - 50)]);
    else if (k < 268) s = (short)h1[row * 168 + (k - 100)];
    else if (k < 436) s = f2b(kk[row * 168 + (k - 268)]);
    else              s = 0;
    r[b] = s;
  }
  return r;
}

// ---------------- GEMM1: leaf cell ----------------
// Block = 64 rows, 8 waves = 2 row-waves x 4 col-waves. Wave: 32 rows x (4 gates x 48 m).
// B from double-buffered LDS (48KB/kt), staged via global_load_lds.
#define G1_NKT 18
#define G1_CHUNK (48 * 1024)
#define G1_LOADS 6

__global__ __launch_bounds__(512, 2) void gemm1_kernel(
    const float* __restrict__ e, const float* __restrict__ tg, const float* __restrict__ tp,
    const float* __restrict__ hp, const float* __restrict__ cprev, const float* __restrict__ b_l,
    const char* __restrict__ B1, float* __restrict__ c1buf, unsigned short* __restrict__ h1buf) {
  __shared__ char lds[2][G1_CHUNK];
  const int tid = threadIdx.x;
  const int wave = tid >> 6, ln = tid & 63;
  const int rw = wave >> 2, cw = wave & 3;
  const int rbase = blockIdx.x * 64 + rw * 32;
  const int c = ln & 15, rg = ln >> 4;

  f32x4 acc[2][12];
  const f32x4 z4 = {0.f, 0.f, 0.f, 0.f};
#pragma unroll
  for (int a = 0; a < 2; ++a)
#pragma unroll
    for (int t = 0; t < 12; ++t) acc[a][t] = z4;

  int r0 = rbase + c;      if (r0 >= NROWS) r0 = NROWS - 1;
  int r1 = rbase + 16 + c; if (r1 >= NROWS) r1 = NROWS - 1;

  // prologue: stage kt=0 into buf 0
#pragma unroll
  for (int j = 0; j < G1_LOADS; ++j)
    gload_lds16(B1 + (j * 512 + tid) * 16, &lds[0][(j * 512 + (wave << 6)) * 16]);
  __syncthreads();

#pragma unroll
  for (int kt = 0; kt < G1_NKT; ++kt) {
    const int cur = kt & 1;
    const int k0 = kt * 32 + (rg << 3);
    bf16x8 a0 = gatherX1(e, tg, tp, hp, r0, k0);
    bf16x8 a1 = gatherX1(e, tg, tp, hp, r1, k0);
    if (kt + 1 < G1_NKT) {
      const char* g = B1 + (kt + 1) * G1_CHUNK;
#pragma unroll
      for (int j = 0; j < G1_LOADS; ++j)
        gload_lds16(g + (j * 512 + tid) * 16, &lds[cur ^ 1][(j * 512 + (wave << 6)) * 16]);
    }
#pragma unroll
    for (int t = 0; t < 12; ++t) {
      const int gate = t / 3, mtl = t % 3;
      const int ct = gate * 12 + cw * 3 + mtl;
      bf16x8 bb = *(const bf16x8*)&lds[cur][((ct << 6) + ln) * 16];
      acc[0][t] = __builtin_amdgcn_mfma_f32_16x16x32_bf16(a0, bb, acc[0][t], 0, 0, 0);
      acc[1][t] = __builtin_amdgcn_mfma_f32_16x16x32_bf16(a1, bb, acc[1][t], 0, 0, 0);
    }
    __syncthreads();
  }

#pragma unroll
  for (int rt = 0; rt < 2; ++rt) {
#pragma unroll
    for (int mtl = 0; mtl < 3; ++mtl) {
      const int m = cw * 48 + mtl * 16 + c;
      if (m >= 168) continue;
      const float bi = b_l[m];
      const float bo = b_l[168 + m];
      const float bf_ = b_l[336 + m];
      const float bu = b_l[504 + m];
#pragma unroll
      for (int reg = 0; reg < 4; ++reg) {
        const int row = rbase + rt * 16 + (rg << 2) + reg;
        if (row >= NROWS) continue;
        const float iv = acc[rt][0 + mtl][reg] + bi;
        const float ov = acc[rt][3 + mtl][reg] + bo;
        const float fv = acc[rt][6 + mtl][reg] + bf_;
        const float uv = acc[rt][9 + mtl][reg] + bu;
        const float cp = cprev[row * 168 + m];
        const float c1 = sigf(iv) * tanh_f(uv) + sigf(fv) * cp;
        const float h1 = sigf(ov) * tanh_f(c1);
        c1buf[row * 168 + m] = c1;
        h1buf[row * 168 + m] = (unsigned short)f2b(h1);
      }
    }
  }
}

// ---------------- GEMM2: node cell ----------------
#define G2_NKT 14
#define G2_CHUNK (64 * 1024)
#define G2_LOADS 8

__global__ __launch_bounds__(512, 2) void gemm2_kernel(
    const float* __restrict__ tg, const float* __restrict__ tp, const float* __restrict__ kk,
    const float* __restrict__ q, const float* __restrict__ b_n,
    const char* __restrict__ B2, const float* __restrict__ c1buf,
    const unsigned short* __restrict__ h1buf, float* __restrict__ out) {
  __shared__ char lds[2][G2_CHUNK];
  const int tid = threadIdx.x;
  const int wave = tid >> 6, ln = tid & 63;
  const int rw = wave >> 2, cw = wave & 3;
  const int rbase = blockIdx.x * 64 + rw * 32;
  const int c = ln & 15, rg = ln >> 4;

  f32x4 acc[2][15];
  const f32x4 z4 = {0.f, 0.f, 0.f, 0.f};
#pragma unroll
  for (int a = 0; a < 2; ++a)
#pragma unroll
    for (int t = 0; t < 15; ++t) acc[a][t] = z4;

  int r0 = rbase + c;      if (r0 >= NROWS) r0 = NROWS - 1;
  int r1 = rbase + 16 + c; if (r1 >= NROWS) r1 = NROWS - 1;

#pragma unroll
  for (int j = 0; j < G2_LOADS; ++j)
    gload_lds16(B2 + (j * 512 + tid) * 16, &lds[0][(j * 512 + (wave << 6)) * 16]);
  __syncthreads();

#pragma unroll
  for (int kt = 0; kt < G2_NKT; ++kt) {
    const int cur = kt & 1;
    const int k0 = kt * 32 + (rg << 3);
    bf16x8 a0 = gatherX2(tg, tp, h1buf, kk, r0, k0);
    bf16x8 a1 = gatherX2(tg, tp, h1buf, kk, r1, k0);
    if (kt + 1 < G2_NKT) {
      const char* g = B2 + (kt + 1) * G2_CHUNK;
#pragma unroll
      for (int j = 0; j < G2_LOADS; ++j)
        gload_lds16(g + (j * 512 + tid) * 16, &lds[cur ^ 1][(j * 512 + (wave << 6)) * 16]);
    }
#pragma unroll
    for (int t = 0; t < 15; ++t) {
      const int gate = t / 3, mtl = t % 3;
      const int ct = gate * 12 + cw * 3 + mtl;
      bf16x8 bb = *(const bf16x8*)&lds[cur][((ct << 6) + ln) * 16];
      acc[0][t] = __builtin_amdgcn_mfma_f32_16x16x32_bf16(a0, bb, acc[0][t], 0, 0, 0);
      acc[1][t] = __builtin_amdgcn_mfma_f32_16x16x32_bf16(a1, bb, acc[1][t], 0, 0, 0);
    }
    __syncthreads();
  }

#pragma unroll
  for (int rt = 0; rt < 2; ++rt) {
#pragma unroll
    for (int mtl = 0; mtl < 3; ++mtl) {
      const int m = cw * 48 + mtl * 16 + c;
      if (m >= 168) continue;
      const float bi = b_n[m];
      const float bo = b_n[168 + m];
      const float bfl = b_n[336 + m];
      const float bfd = b_n[504 + m];
      const float bu = b_n[672 + m];
#pragma unroll
      for (int reg = 0; reg < 4; ++reg) {
        const int row = rbase + rt * 16 + (rg << 2) + reg;
        if (row >= NROWS) continue;
        const float i2 = acc[rt][0 + mtl][reg] + bi;
        const float o2 = acc[rt][3 + mtl][reg] + bo;
        const float fl2 = acc[rt][6 + mtl][reg] + bfl;
        const float fd2 = acc[rt][9 + mtl][reg] + bfd;
        const float u2 = acc[rt][12 + mtl][reg] + bu;
        const int off = row * 168 + m;
        const float c1 = c1buf[off];
        const float qv = q[off];
        const float c2 = sigf(i2) * tanh_f(u2) + sigf(fd2) * qv + sigf(fl2) * c1;
        const float h2 = sigf(o2) * tanh_f(c2);
        out[row * 336 + m] = h2;
        out[row * 336 + 168 + m] = c2;
      }
    }
  }
}

extern "C" void kernel_launch(void* const* d_in, const int* in_sizes, int n_in,
                              void* d_out, int out_size, void* d_ws, size_t ws_size,
                              hipStream_t stream) {
  const float* e     = (const float*)d_in[0];
  const float* tag   = (const float*)d_in[1];
  const float* tagp  = (const float*)d_in[2];
  const float* hprev = (const float*)d_in[3];
  const float* cprev = (const float*)d_in[4];
  const float* kk    = (const float*)d_in[5];
  const float* q     = (const float*)d_in[6];
  const float* We_l  = (const float*)d_in[7];
  const float* Wt_l  = (const float*)d_in[8];
  const float* Wtp_l = (const float*)d_in[9];
  const float* Uh_l  = (const float*)d_in[10];
  const float* b_l   = (const float*)d_in[11];
  const float* Wt_n  = (const float*)d_in[12];
  const float* Wtp_n = (const float*)d_in[13];
  const float* Uh_n  = (const float*)d_in[14];
  const float* Uk_n  = (const float*)d_in[15];
  const float* b_n   = (const float*)d_in[16];
  float* out = (float*)d_out;

  char* ws = (char*)d_ws;
  unsigned short* B1 = (unsigned short*)ws;                            // 884,736 B
  unsigned short* B2 = (unsigned short*)(ws + (1 << 20));              // 917,504 B
  float* c1buf = (float*)(ws + (2 << 20));                             // 67,200,000 B
  unsigned short* h1buf = (unsigned short*)(ws + (2 << 20) + 67200000); // 33,600,000 B

  const int NB = 18 * 48 * 512 + 14 * 64 * 512;
  pack_weights<<<(NB + 255) / 256, 256, 0, stream>>>(We_l, Wt_l, Wtp_l, Uh_l,
                                                     Wt_n, Wtp_n, Uh_n, Uk_n, B1, B2);

  const int nblk = (NROWS + 63) / 64;  // 1563
  gemm1_kernel<<<nblk, 512, 0, stream>>>(e, tag, tagp, hprev, cprev, b_l,
                                         (const char*)B1, c1buf, h1buf);
  gemm2_kernel<<<nblk, 512, 0, stream>>>(tag, tagp, kk, q, b_n,
                                         (const char*)B2, c1buf, h1buf, out);
}

// Round 4
// 557.418 us; speedup vs baseline: 1.6053x; 1.2288x over previous
//
#include <hip/hip_runtime.h>
#include <hip/hip_bf16.h>

#define NROWS 100000

typedef __attribute__((ext_vector_type(8))) short bf16x8;
typedef __attribute__((ext_vector_type(4))) float f32x4;
typedef float f32x4a8 __attribute__((ext_vector_type(4), aligned(8)));

__device__ __forceinline__ short f2b(float f) {
  __hip_bfloat16 h = __float2bfloat16(f);
  short s;
  __builtin_memcpy(&s, &h, sizeof(s));
  return s;
}

__device__ __forceinline__ float b2f(unsigned short u) {
  unsigned v = ((unsigned)u) << 16;
  float f;
  __builtin_memcpy(&f, &v, sizeof(f));
  return f;
}

__device__ __forceinline__ float sigf(float x) { return 1.f / (1.f + __expf(-x)); }
__device__ __forceinline__ float tanh_f(float x) { return 1.f - 2.f / (__expf(2.f * x) + 1.f); }

__device__ __forceinline__ void gload_lds16(const void* g, void* l) {
  __builtin_amdgcn_global_load_lds((const __attribute__((address_space(1))) unsigned int*)g,
                                   (__attribute__((address_space(3))) unsigned int*)l, 16, 0, 0);
}

// ---------------- weight packing (bias folded in as extra K-row) ----------------
// B1: [kt=18][ct=48][lane=64][b=8] bf16; k = kt*32+(lane>>4)*8+b; gate=ct/12,
//     m=(ct%12)*16+(lane&15). K-rows: e(0:300)|tag(300:350)|tagp(350:400)|h(400:568)|bias(568)|0.
// B2: [kt=14][ct=64][lane=64][b=8] bf16; ct<60 real (5 gates x 12 mtiles);
//     K-rows: tag(0:50)|tagp(50:100)|k(100:268)|h1(268:436)|bias(436)|0. Uk only gates 0-3.
__global__ void pack_weights(const float* __restrict__ We_l, const float* __restrict__ Wt_l,
                             const float* __restrict__ Wtp_l, const float* __restrict__ Uh_l,
                             const float* __restrict__ b_l,
                             const float* __restrict__ Wt_n, const float* __restrict__ Wtp_n,
                             const float* __restrict__ Uh_n, const float* __restrict__ Uk_n,
                             const float* __restrict__ b_n,
                             unsigned short* __restrict__ B1, unsigned short* __restrict__ B2) {
  const int NB1 = 18 * 48 * 512;
  const int NB2 = 14 * 64 * 512;
  int idx = blockIdx.x * blockDim.x + threadIdx.x;
  if (idx < NB1) {
    int b = idx & 7, lane = (idx >> 3) & 63, t = idx >> 9;
    int ct = t % 48, kt = t / 48;
    int k = kt * 32 + ((lane >> 4) << 3) + b;
    int gate = ct / 12, m = (ct % 12) * 16 + (lane & 15);
    float v = 0.f;
    if (m < 168) {
      int col = gate * 168 + m;
      if (k < 300)       v = We_l[k * 672 + col];
      else if (k < 350)  v = Wt_l[(k - 300) * 672 + col];
      else if (k < 400)  v = Wtp_l[(k - 350) * 672 + col];
      else if (k < 568)  v = Uh_l[(k - 400) * 672 + col];
      else if (k == 568) v = b_l[col];
    }
    B1[idx] = (unsigned short)f2b(v);
  } else if (idx < NB1 + NB2) {
    int j = idx - NB1;
    int b = j & 7, lane = (j >> 3) & 63, t = j >> 9;
    int ct = t % 64, kt = t / 64;
    int k = kt * 32 + ((lane >> 4) << 3) + b;
    int gate = ct / 12, m = (ct % 12) * 16 + (lane & 15);
    float v = 0.f;
    if (ct < 60 && m < 168) {
      int col = gate * 168 + m;
      if (k < 50)        v = Wt_n[k * 840 + col];
      else if (k < 100)  v = Wtp_n[(k - 50) * 840 + col];
      else if (k < 268)  v = (gate < 4) ? Uk_n[(k - 100) * 672 + gate * 168 + m] : 0.f;
      else if (k < 436)  v = Uh_n[(k - 268) * 840 + col];
      else if (k == 436) v = b_n[col];
    }
    B2[j] = (unsigned short)f2b(v);
  }
}

// aligned-8 float4 load (tag/tagp rows are only 8B aligned)
__device__ __forceinline__ float4 ld4a8(const float* __restrict__ p) {
  f32x4a8 v = *(const f32x4a8*)p;
  return make_float4(v[0], v[1], v[2], v[3]);
}

// ---------------- GEMM1: leaf cell ----------------
#define G1_NKT 18
#define G1_LOADS 6

__global__ __launch_bounds__(512, 2) void gemm1_kernel(
    const float* __restrict__ e, const float* __restrict__ tg, const float* __restrict__ tp,
    const float* __restrict__ hp, const float* __restrict__ cprev,
    const char* __restrict__ B1, unsigned short* __restrict__ c1buf,
    unsigned short* __restrict__ h1buf) {
  __shared__ char bb[2][48 * 1024];
  __shared__ char ab[2][4096];
  const int tid = threadIdx.x;
  const int wave = tid >> 6, ln = tid & 63;
  const int rw = wave >> 2, cw = wave & 3;
  const int rbase = blockIdx.x * 64 + rw * 32;
  const int c = ln & 15, rg = ln >> 4;

  // A staging geometry: thread covers (rowt = tid>>3, 4 f32 cols at (tid&7)*4)
  const int srowt = tid >> 3;
  const int sks = tid & 7;
  int srow = blockIdx.x * 64 + srowt;
  if (srow >= NROWS) srow = NROWS - 1;
  const int sphys = srowt * 64 + ((((sks >> 1) ^ ((srowt >> 1) & 3)) << 4)) + ((sks & 1) << 3);

  // A-chunk loader: X1 = [e|tag|tagp|h|bias(568)|0], c4 = kt*32 + sks*4
  auto loadA = [&](int kt) -> float4 {
    const int c4 = kt * 32 + sks * 4;
    if (c4 + 4 <= 300) return *(const float4*)(e + srow * 300 + c4);
    if (c4 >= 300 && c4 + 4 <= 348) return ld4a8(tg + srow * 50 + (c4 - 300));
    if (c4 == 348)
      return make_float4(tg[srow * 50 + 48], tg[srow * 50 + 49], tp[srow * 50 + 0], tp[srow * 50 + 1]);
    if (c4 >= 352 && c4 + 4 <= 400) return ld4a8(tp + srow * 50 + (c4 - 350));
    if (c4 >= 400 && c4 + 4 <= 568) return *(const float4*)(hp + srow * 168 + (c4 - 400));
    if (c4 == 568) return make_float4(1.f, 0.f, 0.f, 0.f);
    return make_float4(0.f, 0.f, 0.f, 0.f);
  };
  auto storeA = [&](int buf, float4 v) {
    ushort4 w;
    w.x = (unsigned short)f2b(v.x); w.y = (unsigned short)f2b(v.y);
    w.z = (unsigned short)f2b(v.z); w.w = (unsigned short)f2b(v.w);
    *(ushort4*)&ab[buf][sphys] = w;
  };

  f32x4 acc[2][12];
  const f32x4 z4 = {0.f, 0.f, 0.f, 0.f};
#pragma unroll
  for (int a = 0; a < 2; ++a)
#pragma unroll
    for (int t = 0; t < 12; ++t) acc[a][t] = z4;

  // prologue: stage kt=0
  storeA(0, loadA(0));
#pragma unroll
  for (int j = 0; j < G1_LOADS; ++j)
    gload_lds16(B1 + (j * 512 + tid) * 16, &bb[0][(j * 512 + (wave << 6)) * 16]);
  __syncthreads();

  // FIX (round 3 bug): tile rows must include the wave's row-half (rw*32)
  const int r0t = rw * 32 + c, r1t = rw * 32 + 16 + c;
  const int aoff0 = r0t * 64 + ((rg ^ ((r0t >> 1) & 3)) << 4);
  const int aoff1 = r1t * 64 + ((rg ^ ((r1t >> 1) & 3)) << 4);

#pragma unroll
  for (int kt = 0; kt < G1_NKT; ++kt) {
    const int cur = kt & 1, nxt = cur ^ 1;
    bf16x8 a0 = *(const bf16x8*)&ab[cur][aoff0];
    bf16x8 a1 = *(const bf16x8*)&ab[cur][aoff1];
    float4 av;
    if (kt + 1 < G1_NKT) {
      av = loadA(kt + 1);
      const char* g = B1 + (kt + 1) * (48 * 1024);
#pragma unroll
      for (int j = 0; j < G1_LOADS; ++j)
        gload_lds16(g + (j * 512 + tid) * 16, &bb[nxt][(j * 512 + (wave << 6)) * 16]);
    }
#pragma unroll
    for (int t = 0; t < 12; ++t) {
      const int gate = t / 3, mtl = t % 3;
      const int ct = gate * 12 + cw * 3 + mtl;
      bf16x8 bbf = *(const bf16x8*)&bb[cur][((ct << 6) + ln) * 16];
      acc[0][t] = __builtin_amdgcn_mfma_f32_16x16x32_bf16(a0, bbf, acc[0][t], 0, 0, 0);
      acc[1][t] = __builtin_amdgcn_mfma_f32_16x16x32_bf16(a1, bbf, acc[1][t], 0, 0, 0);
    }
    if (kt + 1 < G1_NKT) storeA(nxt, av);
    __syncthreads();
  }

  // epilogue (bias already in acc via K-row 568)
#pragma unroll
  for (int rt = 0; rt < 2; ++rt) {
#pragma unroll
    for (int mtl = 0; mtl < 3; ++mtl) {
      const int m = cw * 48 + mtl * 16 + c;
      if (m >= 168) continue;
#pragma unroll
      for (int reg = 0; reg < 4; ++reg) {
        const int row = rbase + rt * 16 + (rg << 2) + reg;
        if (row >= NROWS) continue;
        const float iv = acc[rt][0 + mtl][reg];
        const float ov = acc[rt][3 + mtl][reg];
        const float fv = acc[rt][6 + mtl][reg];
        const float uv = acc[rt][9 + mtl][reg];
        const int off = row * 168 + m;
        const float cp = cprev[off];
        const float c1 = sigf(iv) * tanh_f(uv) + sigf(fv) * cp;
        const float h1 = sigf(ov) * tanh_f(c1);
        c1buf[off] = (unsigned short)f2b(c1);
        h1buf[off] = (unsigned short)f2b(h1);
      }
    }
  }
}

// ---------------- GEMM2: node cell ----------------
#define G2_NKT 14
#define G2_LOADS 8

__global__ __launch_bounds__(512, 2) void gemm2_kernel(
    const float* __restrict__ tg, const float* __restrict__ tp, const float* __restrict__ kk,
    const float* __restrict__ q, const char* __restrict__ B2,
    const unsigned short* __restrict__ c1buf, const unsigned short* __restrict__ h1buf,
    float* __restrict__ out) {
  __shared__ char bb[2][64 * 1024];
  __shared__ char ab[2][4096];
  const int tid = threadIdx.x;
  const int wave = tid >> 6, ln = tid & 63;
  const int rw = wave >> 2, cw = wave & 3;
  const int rbase = blockIdx.x * 64 + rw * 32;
  const int c = ln & 15, rg = ln >> 4;

  const int srowt = tid >> 3;
  const int sks = tid & 7;
  int srow = blockIdx.x * 64 + srowt;
  if (srow >= NROWS) srow = NROWS - 1;
  const int sphys = srowt * 64 + ((((sks >> 1) ^ ((srowt >> 1) & 3)) << 4)) + ((sks & 1) << 3);

  // X2 = [tag(0:50)|tagp(50:100)|k(100:268)|h1(268:436)|bias(436)|0]
  auto loadA = [&](int kt) -> float4 {
    const int c4 = kt * 32 + sks * 4;
    if (c4 + 4 <= 48) return ld4a8(tg + srow * 50 + c4);
    if (c4 == 48)
      return make_float4(tg[srow * 50 + 48], tg[srow * 50 + 49], tp[srow * 50 + 0], tp[srow * 50 + 1]);
    if (c4 >= 52 && c4 + 4 <= 100) return ld4a8(tp + srow * 50 + (c4 - 50));
    if (c4 >= 100 && c4 + 4 <= 268) return *(const float4*)(kk + srow * 168 + (c4 - 100));
    if (c4 >= 268 && c4 + 4 <= 436) {
      ushort4 w = *(const ushort4*)(h1buf + srow * 168 + (c4 - 268));
      return make_float4(b2f(w.x), b2f(w.y), b2f(w.z), b2f(w.w));
    }
    if (c4 == 436) return make_float4(1.f, 0.f, 0.f, 0.f);
    return make_float4(0.f, 0.f, 0.f, 0.f);
  };
  auto storeA = [&](int buf, float4 v) {
    ushort4 w;
    w.x = (unsigned short)f2b(v.x); w.y = (unsigned short)f2b(v.y);
    w.z = (unsigned short)f2b(v.z); w.w = (unsigned short)f2b(v.w);
    *(ushort4*)&ab[buf][sphys] = w;
  };

  f32x4 acc[2][15];
  const f32x4 z4 = {0.f, 0.f, 0.f, 0.f};
#pragma unroll
  for (int a = 0; a < 2; ++a)
#pragma unroll
    for (int t = 0; t < 15; ++t) acc[a][t] = z4;

  storeA(0, loadA(0));
#pragma unroll
  for (int j = 0; j < G2_LOADS; ++j)
    gload_lds16(B2 + (j * 512 + tid) * 16, &bb[0][(j * 512 + (wave << 6)) * 16]);
  __syncthreads();

  // FIX (round 3 bug): tile rows must include the wave's row-half (rw*32)
  const int r0t = rw * 32 + c, r1t = rw * 32 + 16 + c;
  const int aoff0 = r0t * 64 + ((rg ^ ((r0t >> 1) & 3)) << 4);
  const int aoff1 = r1t * 64 + ((rg ^ ((r1t >> 1) & 3)) << 4);

#pragma unroll
  for (int kt = 0; kt < G2_NKT; ++kt) {
    const int cur = kt & 1, nxt = cur ^ 1;
    bf16x8 a0 = *(const bf16x8*)&ab[cur][aoff0];
    bf16x8 a1 = *(const bf16x8*)&ab[cur][aoff1];
    float4 av;
    if (kt + 1 < G2_NKT) {
      av = loadA(kt + 1);
      const char* g = B2 + (kt + 1) * (64 * 1024);
#pragma unroll
      for (int j = 0; j < G2_LOADS; ++j)
        gload_lds16(g + (j * 512 + tid) * 16, &bb[nxt][(j * 512 + (wave << 6)) * 16]);
    }
#pragma unroll
    for (int t = 0; t < 15; ++t) {
      const int gate = t / 3, mtl = t % 3;
      const int ct = gate * 12 + cw * 3 + mtl;
      bf16x8 bbf = *(const bf16x8*)&bb[cur][((ct << 6) + ln) * 16];
      acc[0][t] = __builtin_amdgcn_mfma_f32_16x16x32_bf16(a0, bbf, acc[0][t], 0, 0, 0);
      acc[1][t] = __builtin_amdgcn_mfma_f32_16x16x32_bf16(a1, bbf, acc[1][t], 0, 0, 0);
    }
    if (kt + 1 < G2_NKT) storeA(nxt, av);
    __syncthreads();
  }

#pragma unroll
  for (int rt = 0; rt < 2; ++rt) {
#pragma unroll
    for (int mtl = 0; mtl < 3; ++mtl) {
      const int m = cw * 48 + mtl * 16 + c;
      if (m >= 168) continue;
#pragma unroll
      for (int reg = 0; reg < 4; ++reg) {
        const int row = rbase + rt * 16 + (rg << 2) + reg;
        if (row >= NROWS) continue;
        const float i2 = acc[rt][0 + mtl][reg];
        const float o2 = acc[rt][3 + mtl][reg];
        const float fl2 = acc[rt][6 + mtl][reg];
        const float fd2 = acc[rt][9 + mtl][reg];
        const float u2 = acc[rt][12 + mtl][reg];
        const int off = row * 168 + m;
        const float c1 = b2f(c1buf[off]);
        const float qv = q[off];
        const float c2 = sigf(i2) * tanh_f(u2) + sigf(fd2) * qv + sigf(fl2) * c1;
        const float h2 = sigf(o2) * tanh_f(c2);
        out[row * 336 + m] = h2;
        out[row * 336 + 168 + m] = c2;
      }
    }
  }
}

extern "C" void kernel_launch(void* const* d_in, const int* in_sizes, int n_in,
                              void* d_out, int out_size, void* d_ws, size_t ws_size,
                              hipStream_t stream) {
  const float* e     = (const float*)d_in[0];
  const float* tag   = (const float*)d_in[1];
  const float* tagp  = (const float*)d_in[2];
  const float* hprev = (const float*)d_in[3];
  const float* cprev = (const float*)d_in[4];
  const float* kk    = (const float*)d_in[5];
  const float* q     = (const float*)d_in[6];
  const float* We_l  = (const float*)d_in[7];
  const float* Wt_l  = (const float*)d_in[8];
  const float* Wtp_l = (const float*)d_in[9];
  const float* Uh_l  = (const float*)d_in[10];
  const float* b_l   = (const float*)d_in[11];
  const float* Wt_n  = (const float*)d_in[12];
  const float* Wtp_n = (const float*)d_in[13];
  const float* Uh_n  = (const float*)d_in[14];
  const float* Uk_n  = (const float*)d_in[15];
  const float* b_n   = (const float*)d_in[16];
  float* out = (float*)d_out;

  char* ws = (char*)d_ws;
  unsigned short* B1 = (unsigned short*)ws;                               // 884,736 B
  unsigned short* B2 = (unsigned short*)(ws + (1 << 20));                 // 917,504 B
  unsigned short* c1buf = (unsigned short*)(ws + (2 << 20));              // 33,600,000 B
  unsigned short* h1buf = (unsigned short*)(ws + (2 << 20) + 33600000);   // 33,600,000 B

  const int NB = 18 * 48 * 512 + 14 * 64 * 512;
  pack_weights<<<(NB + 255) / 256, 256, 0, stream>>>(We_l, Wt_l, Wtp_l, Uh_l, b_l,
                                                     Wt_n, Wtp_n, Uh_n, Uk_n, b_n, B1, B2);

  const int nblk = (NROWS + 63) / 64;  // 1563
  gemm1_kernel<<<nblk, 512, 0, stream>>>(e, tag, tagp, hprev, cprev,
                                         (const char*)B1, c1buf, h1buf);
  gemm2_kernel<<<nblk, 512, 0, stream>>>(tag, tagp, kk, q,
                                         (const char*)B2, c1buf, h1buf, out);
}